// Round 10
// baseline (390.232 us; speedup 1.0000x reference)
//
#include <hip/hip_runtime.h>
#include <hip/hip_bf16.h>

typedef __hip_bfloat16 bf16;
typedef __attribute__((ext_vector_type(8))) short short8v;   // 8 x bf16 (4 VGPR) MFMA frag
typedef __attribute__((ext_vector_type(4))) float f32x4;

__device__ __forceinline__ unsigned int cvtpk(float lo, float hi){
  unsigned int r;
  asm volatile("v_cvt_pk_bf16_f32 %0, %1, %2" : "=v"(r) : "v"(lo), "v"(hi));
  return r;
}
__device__ __forceinline__ float exp2a(float x){
  float r;
  asm volatile("v_exp_f32 %0, %1" : "=v"(r) : "v"(x));
  return r;
}

// ---------- conv 3x3 stride2 pad1 + relu; per-oc block, LDS weights, branch-free ----------
template<int CIN>
__global__ __launch_bounds__(256) void k_conv_s2t(const float* __restrict__ in, const float* __restrict__ w,
    const float* __restrict__ bias, float* __restrict__ out, int Hin, int Win){
  const int Hout = Hin>>1, Wout = Win>>1, HW = Hout*Wout;
  __shared__ float wl[CIN*9];
  const int oc = blockIdx.y, tid = threadIdx.x;
  for(int i=tid;i<CIN*9;i+=256) wl[i] = w[oc*CIN*9 + i];
  __syncthreads();
  const int idx = blockIdx.x*256 + tid;
  if(idx >= HW) return;
  const int oy = idx/Wout, ox = idx - oy*Wout;
  const int iy0 = 2*oy-1, ix0 = 2*ox-1;
  const float mt = iy0>=0 ? 1.f:0.f, ml = ix0>=0 ? 1.f:0.f;
  const int iyc = iy0<0?0:iy0, ixc = ix0<0?0:ix0;
  const int x1 = ix0+1, x2 = ix0+2;
  float acc = bias[oc];
  #pragma unroll 4
  for(int ic=0; ic<CIN; ++ic){
    const float* b0 = in + (ic*Hin + iyc )*Win;
    const float* b1 = in + (ic*Hin + iy0+1)*Win;
    const float* b2 = in + (ic*Hin + iy0+2)*Win;
    const float* wp = wl + ic*9;
    float t00 = b0[ixc]*(mt*ml), t01 = b0[x1]*mt, t02 = b0[x2]*mt;
    float t10 = b1[ixc]*ml,      t11 = b1[x1],    t12 = b1[x2];
    float t20 = b2[ixc]*ml,      t21 = b2[x1],    t22 = b2[x2];
    acc += t00*wp[0]+t01*wp[1]+t02*wp[2]
         + t10*wp[3]+t11*wp[4]+t12*wp[5]
         + t20*wp[6]+t21*wp[7]+t22*wp[8];
  }
  out[oc*HW + idx] = fmaxf(acc, 0.f);
}

// ---------- q/k/v projections, TPN threads per token; v stored bf16 ----------
template<int C, int O, int TPN>
__global__ __launch_bounds__(256) void k_qkv(const float* __restrict__ x,  // [C][N]
    const float* __restrict__ wq, const float* __restrict__ bq,
    const float* __restrict__ wk, const float* __restrict__ bk,
    const float* __restrict__ wv, const float* __restrict__ bv,
    float* __restrict__ q, float* __restrict__ k, bf16* __restrict__ v, int N){
  constexpr int NPB = 256/TPN;
  constexpr int OP = O/TPN > 0 ? O/TPN : 1;
  constexpr int CP = C/TPN;
  const int n = blockIdx.x*NPB + threadIdx.x/TPN;
  const int p = threadIdx.x%TPN;
  float xc[C];
  #pragma unroll
  for(int c=0;c<C;++c) xc[c] = x[c*N+n];
  #pragma unroll
  for(int oo=0;oo<OP;++oo){
    int o = p*OP + oo;
    float aq = bq[o], ak = bk[o];
    #pragma unroll
    for(int c=0;c<C;++c){ aq += wq[o*C+c]*xc[c]; ak += wk[o*C+c]*xc[c]; }
    q[n*O+o] = aq;
    k[o*N+n] = ak;
  }
  #pragma unroll
  for(int cc=0;cc<CP;++cc){
    int o = p*CP + cc;
    float av = bv[o];
    #pragma unroll
    for(int c=0;c<C;++c) av += wv[o*C+c]*xc[c];
    v[o*N+n] = __float2bfloat16(av);
  }
}

// ---------- MFMA flash attention, partial (key-split), QG query-groups/wave ----------
// Q pre-scaled by log2(e); p = exp2(s') = e^s via raw v_exp_f32.
template<int C, int O, int ST, int NSPLIT, int QG>
__global__ __launch_bounds__(256) void k_attn_mfma(
    const float* __restrict__ q, const float* __restrict__ kk, const bf16* __restrict__ vb,
    float* __restrict__ pacc, float* __restrict__ pden, int N){
  constexpr int NT = C/16;
  constexpr int OF4 = O/4;
  constexpr int VROW = ST*2 + 16;        // bytes
  __shared__ __align__(16) char vsm[C*VROW];
  __shared__ float4 ksm4[(ST + ST/8)*OF4];
  const int tid = threadIdx.x;
  const int qblk = blockIdx.x / NSPLIT, split = blockIdx.x % NSPLIT;
  const int KEYS = N / NSPLIT;
  const int kbase = split * KEYS;
  const int wv = tid >> 6;
  const int l  = tid & 63;
  const int lg = l >> 4, lq = l & 15;
  const int qbase = qblk*(64*QG) + wv*(16*QG);
  float qv[QG][O];
  #pragma unroll
  for(int g=0; g<QG; ++g)
    #pragma unroll
    for(int o=0;o<O;++o) qv[g][o] = q[(qbase + g*16 + lq)*O + o] * 1.44269504f;
  f32x4 acc[QG][NT];
  #pragma unroll
  for(int g=0; g<QG; ++g)
    #pragma unroll
    for(int nt=0;nt<NT;++nt) acc[g][nt] = (f32x4){0.f,0.f,0.f,0.f};
  float den[QG];
  #pragma unroll
  for(int g=0; g<QG; ++g) den[g] = 0.f;

  for(int g0=0; g0<KEYS; g0+=ST){
    __syncthreads();
    for(int j=tid; j<ST; j+=256){
      int row = j + (j>>3);
      #pragma unroll
      for(int h=0;h<OF4;++h){
        float4 kv;
        ((float*)&kv)[0] = kk[(h*4+0)*N + kbase + g0 + j];
        ((float*)&kv)[1] = kk[(h*4+1)*N + kbase + g0 + j];
        ((float*)&kv)[2] = kk[(h*4+2)*N + kbase + g0 + j];
        ((float*)&kv)[3] = kk[(h*4+3)*N + kbase + g0 + j];
        ksm4[row*OF4 + h] = kv;
      }
    }
    for(int ch=tid; ch < C*(ST/8); ch += 256){
      int c = ch / (ST/8), j8 = ch % (ST/8);
      *(uint4*)(vsm + c*VROW + j8*16) =
          *(const uint4*)(vb + (size_t)c*N + kbase + g0 + j8*8);
    }
    __syncthreads();
    #pragma unroll
    for(int s=0; s<ST/32; ++s){
      float pr[QG][8];
      #pragma unroll
      for(int e=0; e<8; ++e){
        const int row = s*36 + lg*9 + e;
        #pragma unroll
        for(int g=0; g<QG; ++g){
          float sc = 0.f;
          #pragma unroll
          for(int h=0;h<OF4;++h){
            float4 k4 = ksm4[row*OF4 + h];
            sc += qv[g][h*4+0]*k4.x + qv[g][h*4+1]*k4.y + qv[g][h*4+2]*k4.z + qv[g][h*4+3]*k4.w;
          }
          pr[g][e] = exp2a(sc);
        }
      }
      union { unsigned int u[4]; short8v s8; } pa[QG];
      #pragma unroll
      for(int g=0; g<QG; ++g){
        #pragma unroll
        for(int u=0; u<4; ++u) pa[g].u[u] = cvtpk(pr[g][2*u], pr[g][2*u+1]);
        #pragma unroll
        for(int e=0; e<8; ++e) den[g] += pr[g][e];
      }
      #pragma unroll
      for(int nt=0; nt<NT; ++nt){
        short8v bf_ = *(const short8v*)(vsm + (lq + nt*16)*VROW + (s*32 + lg*8)*2);
        #pragma unroll
        for(int g=0; g<QG; ++g)
          acc[g][nt] = __builtin_amdgcn_mfma_f32_16x16x32_bf16(pa[g].s8, bf_, acc[g][nt], 0,0,0);
      }
    }
  }
  #pragma unroll
  for(int g=0; g<QG; ++g){
    den[g] += __shfl_xor(den[g], 16);
    den[g] += __shfl_xor(den[g], 32);
    if(lg == 0) pden[(size_t)split*N + qbase + g*16 + lq] = den[g];
  }
  #pragma unroll
  for(int g=0; g<QG; ++g)
    #pragma unroll
    for(int nt=0; nt<NT; ++nt)
      #pragma unroll
      for(int r=0;r<4;++r){
        int qg_ = qbase + g*16 + lg*4 + r;
        pacc[((size_t)split*N + qg_)*C + nt*16 + lq] = acc[g][nt][r];
      }
}

// ---------- attention combine ----------
template<int C, int NSPLIT>
__global__ __launch_bounds__(256) void k_attn_comb(const float* __restrict__ pacc, const float* __restrict__ pden,
    const float* __restrict__ xin, const float* __restrict__ gamma, float* __restrict__ out, int N){
  int idx = blockIdx.x*256 + threadIdx.x;
  if(idx >= N*C) return;
  int c = idx / N, m = idx - c*N;
  float a = 0.f, d = 0.f;
  #pragma unroll
  for(int s=0;s<NSPLIT;++s){
    a += pacc[((size_t)s*N + m)*C + c];
    d += pden[(size_t)s*N + m];
  }
  out[idx] = gamma[0]*a/d + xin[idx];
}

// ---------- fc_mu / fc_lv partials: (1568,2) grid, 64-row chunks, one matrix/block ----------
__global__ __launch_bounds__(256) void k_fc2_part(const float* __restrict__ hf,
    const float* __restrict__ wmu, const float* __restrict__ wlv,
    float* __restrict__ pmu, float* __restrict__ plv){
  __shared__ float sh[64];
  __shared__ float4 red[4][64];
  const int t = threadIdx.x, blk = blockIdx.x, f0 = blk*64;
  const int w = t>>6, l = t&63;
  const float* wsel = blockIdx.y ? wlv : wmu;
  float*       dsel = blockIdx.y ? plv : pmu;
  if(t < 64) sh[t] = hf[f0+t];
  __syncthreads();
  const float4* wp = (const float4*)(wsel + (size_t)(f0 + w*16)*256) + l;
  f32x4 a = {0.f,0.f,0.f,0.f};
  #pragma unroll
  for(int r=0; r<16; ++r){
    float h = sh[w*16 + r];
    float4 u = wp[r*64];
    a[0] += h*u.x; a[1] += h*u.y; a[2] += h*u.z; a[3] += h*u.w;
  }
  red[w][l] = (float4){a[0],a[1],a[2],a[3]};
  __syncthreads();
  const float* rr = (const float*)red;
  dsel[(size_t)blk*256 + t] = rr[t] + rr[256+t] + rr[512+t] + rr[768+t];
}

// ---------- reduce partials + reparametrize; block-per-output ----------
__global__ __launch_bounds__(256) void k_reparam_p(const float* __restrict__ pmu, const float* __restrict__ plv,
    const float* __restrict__ bmu, const float* __restrict__ blv, const float* __restrict__ eps,
    float* __restrict__ z, float* __restrict__ omu, float* __restrict__ olv){
  const int o = blockIdx.x, t = threadIdx.x;
  __shared__ float rm[4], rl[4];
  float sm = 0.f, sl = 0.f;
  for(int j=t; j<1568; j+=256){ sm += pmu[(size_t)j*256+o]; sl += plv[(size_t)j*256+o]; }
  #pragma unroll
  for(int off=32; off>=1; off>>=1){ sm += __shfl_xor(sm, off); sl += __shfl_xor(sl, off); }
  if((t&63)==0){ rm[t>>6]=sm; rl[t>>6]=sl; }
  __syncthreads();
  if(t==0){
    float mu = bmu[o] + rm[0]+rm[1]+rm[2]+rm[3];
    float lv = blv[o] + rl[0]+rl[1]+rl[2]+rl[3];
    z[o] = mu + eps[o] * expf(0.5f*lv);
    omu[o] = mu;
    olv[o] = lv;
  }
}

// ---------- decoder fc partials: (98, OSPL) grid ----------
template<int OSPL>
__global__ __launch_bounds__(256) void k_fc_dec_p(const float* __restrict__ z, const float* __restrict__ w,
    float* __restrict__ pfd){
  constexpr int OPC = 256/OSPL;
  __shared__ float sz[OPC];
  const int t = threadIdx.x, blk = blockIdx.x, os = blockIdx.y;
  if(t<OPC) sz[t] = z[os*OPC + t];
  __syncthreads();
  const size_t f4 = (size_t)blk*256 + t;        // float4 index into 25088
  const float4* wp = (const float4*)w + (size_t)os*OPC*25088 + f4;
  f32x4 a = {0.f,0.f,0.f,0.f};
  #pragma unroll 8
  for(int o=0;o<OPC;++o){
    float zz = sz[o];
    float4 u = wp[(size_t)o*25088];
    a[0] += zz*u.x; a[1] += zz*u.y; a[2] += zz*u.z; a[3] += zz*u.w;
  }
  ((float4*)pfd)[(size_t)os*25088 + f4] = (float4){a[0],a[1],a[2],a[3]};
}

// ---------- decoder fc combine: relu(sum partials + bias) ----------
template<int OSPL>
__global__ __launch_bounds__(256) void k_fc_dec_c(const float* __restrict__ pfd, const float* __restrict__ b,
    float* __restrict__ out){
  const int i = blockIdx.x*256 + threadIdx.x;   // float4 index
  const float4* p4 = (const float4*)pfd;
  float4 bb = ((const float4*)b)[i];
  f32x4 s = {bb.x, bb.y, bb.z, bb.w};
  #pragma unroll
  for(int k=0;k<OSPL;++k){
    float4 u = p4[(size_t)k*25088 + i];
    s[0] += u.x; s[1] += u.y; s[2] += u.z; s[3] += u.w;
  }
  ((float4*)out)[i] = (float4){fmaxf(s[0],0.f), fmaxf(s[1],0.f), fmaxf(s[2],0.f), fmaxf(s[3],0.f)};
}

// ---------- transposed conv 3x3 s2 p1 op1, parity-decomposed ----------
template<int CIN, int COUT, int ACT>
__global__ __launch_bounds__(256) void k_deconv_p(const float* __restrict__ in, const float* __restrict__ w,
    const float* __restrict__ bias, float* __restrict__ out, int Hin, int Win){
  __shared__ float wl[CIN*9];
  const int oc = blockIdx.y;
  const int tid = threadIdx.x;
  for(int i=tid; i<CIN*9; i+=256) wl[i] = w[((i/9)*COUT + oc)*9 + (i%9)];
  __syncthreads();
  const int nq = Hin*Win;
  const int code = blockIdx.x*256 + tid;
  if(code >= 4*nq) return;
  const int q = code % nq;
  const int pcode = code / nq;
  const int px = pcode & 1, py = pcode >> 1;
  const int qy = q / Win, qx = q - qy*Win;
  const float m1x = (qx+1 < Win) ? 1.f : 0.f;
  const float m1y = (qy+1 < Hin) ? 1.f : 0.f;
  const int qxc = (qx+1 < Win) ? qx+1 : qx;
  const int qyc = (qy+1 < Hin) ? qy+1 : qy;
  const int o00 = qy*Win+qx, o01 = qy*Win+qxc, o10 = qyc*Win+qx, o11 = qyc*Win+qxc;
  const int HW = nq;
  float acc = bias[oc];
  if(pcode == 0){
    #pragma unroll 4
    for(int ic=0; ic<CIN; ++ic) acc += in[ic*HW + o00] * wl[ic*9+4];
  } else if(pcode == 1){
    #pragma unroll 4
    for(int ic=0; ic<CIN; ++ic){
      acc += in[ic*HW + o00] * wl[ic*9+5];
      acc += (in[ic*HW + o01]*m1x) * wl[ic*9+3];
    }
  } else if(pcode == 2){
    #pragma unroll 4
    for(int ic=0; ic<CIN; ++ic){
      acc += in[ic*HW + o00] * wl[ic*9+7];
      acc += (in[ic*HW + o10]*m1y) * wl[ic*9+1];
    }
  } else {
    #pragma unroll 4
    for(int ic=0; ic<CIN; ++ic){
      acc += in[ic*HW + o00] * wl[ic*9+8];
      acc += (in[ic*HW + o01]*m1x) * wl[ic*9+6];
      acc += (in[ic*HW + o10]*m1y) * wl[ic*9+2];
      acc += (in[ic*HW + o11]*(m1x*m1y)) * wl[ic*9+0];
    }
  }
  const int oy = 2*qy+py, ox = 2*qx+px;
  float r = (ACT==0) ? fmaxf(acc, 0.f) : 1.f/(1.f + __expf(-acc));
  out[(oc*2*Hin + oy)*2*Win + ox] = r;
}

extern "C" void kernel_launch(void* const* d_in, const int* in_sizes, int n_in,
                              void* d_out, int out_size, void* d_ws, size_t ws_size,
                              hipStream_t stream){
  const float* X    = (const float*)d_in[0];
  const float* EPS  = (const float*)d_in[1];
  const float* c1w  = (const float*)d_in[2];  const float* c1b = (const float*)d_in[3];
  const float* q1w  = (const float*)d_in[4];  const float* q1b = (const float*)d_in[5];
  const float* k1w  = (const float*)d_in[6];  const float* k1b = (const float*)d_in[7];
  const float* v1w  = (const float*)d_in[8];  const float* v1b = (const float*)d_in[9];
  const float* g1   = (const float*)d_in[10];
  const float* c2w  = (const float*)d_in[11]; const float* c2b = (const float*)d_in[12];
  const float* q2w  = (const float*)d_in[13]; const float* q2b = (const float*)d_in[14];
  const float* k2w  = (const float*)d_in[15]; const float* k2b = (const float*)d_in[16];
  const float* v2w  = (const float*)d_in[17]; const float* v2b = (const float*)d_in[18];
  const float* g2   = (const float*)d_in[19];
  const float* c3w  = (const float*)d_in[20]; const float* c3b = (const float*)d_in[21];
  const float* fmw  = (const float*)d_in[22]; const float* fmb = (const float*)d_in[23];
  const float* flw  = (const float*)d_in[24]; const float* flb = (const float*)d_in[25];
  const float* fdw  = (const float*)d_in[26]; const float* fdb = (const float*)d_in[27];
  const float* d1w  = (const float*)d_in[28]; const float* d1b = (const float*)d_in[29];
  const float* d2w  = (const float*)d_in[30]; const float* d2b = (const float*)d_in[31];
  const float* d3w  = (const float*)d_in[32]; const float* d3b = (const float*)d_in[33];

  float* ws  = (float*)d_ws;
  float* h1  = ws;            // 401408
  float* h1a = h1  + 401408;  // 401408
  float* q1  = h1a + 401408;  // 50176
  float* k1  = q1  + 50176;   // 50176
  float* v1f = k1  + 50176;   // 401408 slot; bf16 [32][12544]
  float* h2  = v1f + 401408;  // 200704
  float* h2a = h2  + 200704;  // 200704
  float* q2  = h2a + 200704;  // 25088
  float* k2  = q2  + 25088;   // 25088
  float* v2f = k2  + 25088;   // 200704 slot; bf16 [64][3136]
  float* h3  = v2f + 200704;  // 100352
  float* z   = h3  + 100352 + 200704;  // 256
  float* part= h3  + 100352 + 200704 + 256;  // attn partial region
  bf16* v1b_ = (bf16*)v1f;
  bf16* v2b_ = (bf16*)v2f;
  // fc partials alias the (dead-by-then) attn partial region:
  float* pmu = part;              // [1568][256] = 401408
  float* plv = part + 401408;     // [1568][256] = 401408
  float* pfd = part + 802816;     // up to [16][100352] = 1605632
  // decoder buffers alias dead encoder regions:
  float* dd0 = h1;            // 100352
  float* dd1 = h1 + 100352;   // 200704
  float* dd2 = h1a;           // 401408

  const size_t base = 2258176;
  const bool big = ws_size >= (base + 2809856 + 87808) * 4;  // NSPLIT=7 footprint
  float* pdn = part + (big ? 2809856 : 802816);

  float* OUT = (float*)d_out;   // [recon 150528 | mu 256 | logvar 256], all f32

  k_conv_s2t<3><<<dim3(49,32),dim3(256),0,stream>>>(X, c1w, c1b, h1, 224, 224);
  k_qkv<32,4,4><<<dim3(196),dim3(256),0,stream>>>(h1, q1w,q1b, k1w,k1b, v1w,v1b, q1,k1,v1b_, 12544);
  if(big){
    k_attn_mfma<32,4,128,7,2><<<dim3(686),dim3(256),0,stream>>>(q1,k1,v1b_, part, pdn, 12544);
    k_attn_comb<32,7><<<dim3(1568),dim3(256),0,stream>>>(part, pdn, h1, g1, h1a, 12544);
  } else {
    k_attn_mfma<32,4,128,2,2><<<dim3(196),dim3(256),0,stream>>>(q1,k1,v1b_, part, pdn, 12544);
    k_attn_comb<32,2><<<dim3(1568),dim3(256),0,stream>>>(part, pdn, h1, g1, h1a, 12544);
  }
  k_conv_s2t<32><<<dim3(13,64),dim3(256),0,stream>>>(h1a, c2w, c2b, h2, 112, 112);
  k_qkv<64,8,8><<<dim3(98),dim3(256),0,stream>>>(h2, q2w,q2b, k2w,k2b, v2w,v2b, q2,k2,v2b_, 3136);
  if(big){
    k_attn_mfma<64,8,64,7,1><<<dim3(343),dim3(256),0,stream>>>(q2,k2,v2b_, part, pdn, 3136);
    k_attn_comb<64,7><<<dim3(784),dim3(256),0,stream>>>(part, pdn, h2, g2, h2a, 3136);
  } else {
    k_attn_mfma<64,8,64,1,1><<<dim3(49),dim3(256),0,stream>>>(q2,k2,v2b_, part, pdn, 3136);
    k_attn_comb<64,1><<<dim3(784),dim3(256),0,stream>>>(part, pdn, h2, g2, h2a, 3136);
  }
  k_conv_s2t<64><<<dim3(4,128),dim3(256),0,stream>>>(h2a, c3w, c3b, h3, 56, 56);
  k_fc2_part<<<dim3(1568,2),dim3(256),0,stream>>>(h3, fmw, flw, pmu, plv);
  k_reparam_p<<<dim3(256),dim3(256),0,stream>>>(pmu, plv, fmb, flb, EPS, z, OUT+150528, OUT+150784);
  if(big){
    k_fc_dec_p<16><<<dim3(98,16),dim3(256),0,stream>>>(z, fdw, pfd);
    k_fc_dec_c<16><<<dim3(98),dim3(256),0,stream>>>(pfd, fdb, dd0);
  } else {
    k_fc_dec_p<4><<<dim3(98,4),dim3(256),0,stream>>>(z, fdw, pfd);
    k_fc_dec_c<4><<<dim3(98),dim3(256),0,stream>>>(pfd, fdb, dd0);
  }
  k_deconv_p<128,64,0><<<dim3(13,64),dim3(256),0,stream>>>(dd0, d1w, d1b, dd1, 28,28);
  k_deconv_p<64,32,0><<<dim3(49,32),dim3(256),0,stream>>>(dd1, d2w, d2b, dd2, 56,56);
  k_deconv_p<32,3,1><<<dim3(196,3),dim3(256),0,stream>>>(dd2, d3w, d3b, OUT, 112,112);
}

// Round 11
// 351.713 us; speedup vs baseline: 1.1095x; 1.1095x over previous
//
#include <hip/hip_runtime.h>
#include <hip/hip_bf16.h>

typedef __hip_bfloat16 bf16;
typedef __attribute__((ext_vector_type(8))) short short8v;   // 8 x bf16 (4 VGPR) MFMA frag
typedef __attribute__((ext_vector_type(4))) float f32x4;

__device__ __forceinline__ unsigned int cvtpk(float lo, float hi){
  unsigned int r;
  asm("v_cvt_pk_bf16_f32 %0, %1, %2" : "=v"(r) : "v"(lo), "v"(hi));
  return r;
}
__device__ __forceinline__ float exp2a(float x){
  float r;
  asm("v_exp_f32 %0, %1" : "=v"(r) : "v"(x));
  return r;
}

// ---------- conv 3x3 stride2 pad1 + relu; per-oc block, LDS weights, branch-free ----------
template<int CIN>
__global__ __launch_bounds__(256) void k_conv_s2t(const float* __restrict__ in, const float* __restrict__ w,
    const float* __restrict__ bias, float* __restrict__ out, int Hin, int Win){
  const int Hout = Hin>>1, Wout = Win>>1, HW = Hout*Wout;
  __shared__ float wl[CIN*9];
  const int oc = blockIdx.y, tid = threadIdx.x;
  for(int i=tid;i<CIN*9;i+=256) wl[i] = w[oc*CIN*9 + i];
  __syncthreads();
  const int idx = blockIdx.x*256 + tid;
  if(idx >= HW) return;
  const int oy = idx/Wout, ox = idx - oy*Wout;
  const int iy0 = 2*oy-1, ix0 = 2*ox-1;
  const float mt = iy0>=0 ? 1.f:0.f, ml = ix0>=0 ? 1.f:0.f;
  const int iyc = iy0<0?0:iy0, ixc = ix0<0?0:ix0;
  const int x1 = ix0+1, x2 = ix0+2;
  float acc = bias[oc];
  #pragma unroll 4
  for(int ic=0; ic<CIN; ++ic){
    const float* b0 = in + (ic*Hin + iyc )*Win;
    const float* b1 = in + (ic*Hin + iy0+1)*Win;
    const float* b2 = in + (ic*Hin + iy0+2)*Win;
    const float* wp = wl + ic*9;
    float t00 = b0[ixc]*(mt*ml), t01 = b0[x1]*mt, t02 = b0[x2]*mt;
    float t10 = b1[ixc]*ml,      t11 = b1[x1],    t12 = b1[x2];
    float t20 = b2[ixc]*ml,      t21 = b2[x1],    t22 = b2[x2];
    acc += t00*wp[0]+t01*wp[1]+t02*wp[2]
         + t10*wp[3]+t11*wp[4]+t12*wp[5]
         + t20*wp[6]+t21*wp[7]+t22*wp[8];
  }
  out[oc*HW + idx] = fmaxf(acc, 0.f);
}

// ---------- q/k/v projections, TPN threads per token; v stored bf16 ----------
template<int C, int O, int TPN>
__global__ __launch_bounds__(256) void k_qkv(const float* __restrict__ x,  // [C][N]
    const float* __restrict__ wq, const float* __restrict__ bq,
    const float* __restrict__ wk, const float* __restrict__ bk,
    const float* __restrict__ wv, const float* __restrict__ bv,
    float* __restrict__ q, float* __restrict__ k, bf16* __restrict__ v, int N){
  constexpr int NPB = 256/TPN;
  constexpr int OP = O/TPN > 0 ? O/TPN : 1;
  constexpr int CP = C/TPN;
  const int n = blockIdx.x*NPB + threadIdx.x/TPN;
  const int p = threadIdx.x%TPN;
  float xc[C];
  #pragma unroll
  for(int c=0;c<C;++c) xc[c] = x[c*N+n];
  #pragma unroll
  for(int oo=0;oo<OP;++oo){
    int o = p*OP + oo;
    float aq = bq[o], ak = bk[o];
    #pragma unroll
    for(int c=0;c<C;++c){ aq += wq[o*C+c]*xc[c]; ak += wk[o*C+c]*xc[c]; }
    q[n*O+o] = aq;
    k[o*N+n] = ak;
  }
  #pragma unroll
  for(int cc=0;cc<CP;++cc){
    int o = p*CP + cc;
    float av = bv[o];
    #pragma unroll
    for(int c=0;c<C;++c) av += wv[o*C+c]*xc[c];
    v[o*N+n] = __float2bfloat16(av);
  }
}

// ---------- MFMA flash attention, key-split, QG q-groups/wave, double-buffered LDS ----------
// Per tile: issue next-tile global loads -> compute current LDS buffer -> write regs to
// alternate buffer -> one barrier. Global latency hides under compute.
template<int C, int O, int ST, int NSPLIT, int QG>
__global__ __launch_bounds__(256) void k_attn_mfma(
    const float* __restrict__ q, const float* __restrict__ kk, const bf16* __restrict__ vb,
    float* __restrict__ pacc, float* __restrict__ pden, int N){
  constexpr int NT = C/16;
  constexpr int OF4 = O/4;
  constexpr int VROW = ST*2 + 16;        // bytes
  constexpr int VIT  = C*(ST/8)/256;     // uint4 stages per thread (=2 here)
  __shared__ __align__(16) char vsm[2][C*VROW];
  __shared__ float4 ksm4[2][(ST + ST/8)*OF4];
  const int tid = threadIdx.x;
  const int qblk = blockIdx.x / NSPLIT, split = blockIdx.x % NSPLIT;
  const int KEYS = N / NSPLIT;
  const int kbase = split * KEYS;
  const int wv = tid >> 6;
  const int l  = tid & 63;
  const int lg = l >> 4, lq = l & 15;
  const int qbase = qblk*(64*QG) + wv*(16*QG);
  float qv[QG][O];
  #pragma unroll
  for(int g=0; g<QG; ++g)
    #pragma unroll
    for(int o=0;o<O;++o) qv[g][o] = q[(qbase + g*16 + lq)*O + o] * 1.44269504f;
  f32x4 acc[QG][NT];
  #pragma unroll
  for(int g=0; g<QG; ++g)
    #pragma unroll
    for(int nt=0;nt<NT;++nt) acc[g][nt] = (f32x4){0.f,0.f,0.f,0.f};
  float den[QG];
  #pragma unroll
  for(int g=0; g<QG; ++g) den[g] = 0.f;

  float4 kreg[OF4];
  uint4  vreg[VIT];
  const bool kact = tid < ST;

  auto LOAD = [&](int g0){
    if(kact){
      #pragma unroll
      for(int h=0;h<OF4;++h){
        ((float*)&kreg[h])[0] = kk[(h*4+0)*N + kbase + g0 + tid];
        ((float*)&kreg[h])[1] = kk[(h*4+1)*N + kbase + g0 + tid];
        ((float*)&kreg[h])[2] = kk[(h*4+2)*N + kbase + g0 + tid];
        ((float*)&kreg[h])[3] = kk[(h*4+3)*N + kbase + g0 + tid];
      }
    }
    #pragma unroll
    for(int i=0;i<VIT;++i){
      int ch = i*256 + tid;
      int c = ch/(ST/8), j8 = ch%(ST/8);
      vreg[i] = *(const uint4*)(vb + (size_t)c*N + kbase + g0 + j8*8);
    }
  };
  auto STORE = [&](int b){
    if(kact){
      int row = tid + (tid>>3);
      #pragma unroll
      for(int h=0;h<OF4;++h) ksm4[b][row*OF4 + h] = kreg[h];
    }
    #pragma unroll
    for(int i=0;i<VIT;++i){
      int ch = i*256 + tid;
      int c = ch/(ST/8), j8 = ch%(ST/8);
      *(uint4*)(vsm[b] + c*VROW + j8*16) = vreg[i];
    }
  };

  const int NTILE = KEYS/ST;
  LOAD(0);
  STORE(0);
  __syncthreads();
  int cur = 0;
  for(int t=0; t<NTILE; ++t){
    if(t+1 < NTILE) LOAD((t+1)*ST);
    // ---- compute tile from buffer cur ----
    #pragma unroll
    for(int s=0; s<ST/32; ++s){
      float pr[QG][8];
      #pragma unroll
      for(int e=0; e<8; ++e){
        const int row = s*36 + lg*9 + e;
        #pragma unroll
        for(int g=0; g<QG; ++g){
          float sc = 0.f;
          #pragma unroll
          for(int h=0;h<OF4;++h){
            float4 k4 = ksm4[cur][row*OF4 + h];
            sc += qv[g][h*4+0]*k4.x + qv[g][h*4+1]*k4.y + qv[g][h*4+2]*k4.z + qv[g][h*4+3]*k4.w;
          }
          pr[g][e] = exp2a(sc);
        }
      }
      union { unsigned int u[4]; short8v s8; } pa[QG];
      #pragma unroll
      for(int g=0; g<QG; ++g){
        #pragma unroll
        for(int u=0; u<4; ++u) pa[g].u[u] = cvtpk(pr[g][2*u], pr[g][2*u+1]);
        #pragma unroll
        for(int e=0; e<8; ++e) den[g] += pr[g][e];
      }
      #pragma unroll
      for(int nt=0; nt<NT; ++nt){
        short8v bf_ = *(const short8v*)(vsm[cur] + (lq + nt*16)*VROW + (s*32 + lg*8)*2);
        #pragma unroll
        for(int g=0; g<QG; ++g)
          acc[g][nt] = __builtin_amdgcn_mfma_f32_16x16x32_bf16(pa[g].s8, bf_, acc[g][nt], 0,0,0);
      }
    }
    if(t+1 < NTILE) STORE(cur^1);
    __syncthreads();
    cur ^= 1;
  }
  #pragma unroll
  for(int g=0; g<QG; ++g){
    den[g] += __shfl_xor(den[g], 16);
    den[g] += __shfl_xor(den[g], 32);
    if(lg == 0) pden[(size_t)split*N + qbase + g*16 + lq] = den[g];
  }
  #pragma unroll
  for(int g=0; g<QG; ++g)
    #pragma unroll
    for(int nt=0; nt<NT; ++nt)
      #pragma unroll
      for(int r=0;r<4;++r){
        int qg_ = qbase + g*16 + lg*4 + r;
        pacc[((size_t)split*N + qg_)*C + nt*16 + lq] = acc[g][nt][r];
      }
}

// ---------- attention combine, token-major + LDS transpose (coalesced both phases) ----------
template<int C, int NSPLIT>
__global__ __launch_bounds__(256) void k_attn_combT(const float* __restrict__ pacc,
    const float* __restrict__ pden, const float* __restrict__ xin,
    const float* __restrict__ gamma, float* __restrict__ out, int N){
  __shared__ float tl[C][65];
  __shared__ float dl[64];
  const int t = threadIdx.x;
  const int m0 = blockIdx.x*64;
  if(t < 64){
    float d = 0.f;
    #pragma unroll
    for(int s=0;s<NSPLIT;++s) d += pden[(size_t)s*N + m0 + t];
    dl[t] = d;
  }
  constexpr int E = 64*C/256;
  #pragma unroll
  for(int e=0;e<E;++e){
    int f = e*256 + t;                 // f = ml*C + c  (linear in pacc)
    int ml = f/C, c = f - ml*C;
    float a = 0.f;
    #pragma unroll
    for(int s=0;s<NSPLIT;++s) a += pacc[(size_t)s*N*C + (size_t)m0*C + f];
    tl[c][ml] = a;
  }
  __syncthreads();
  const float gm = gamma[0];
  #pragma unroll
  for(int e=0;e<E;++e){
    int f = e*256 + t;                 // f = c*64 + ml (linear in out/xin)
    int c = f>>6, ml = f & 63;
    size_t gi = (size_t)c*N + m0 + ml;
    out[gi] = gm * tl[c][ml] / dl[ml] + xin[gi];
  }
}

// ---------- fc_mu / fc_lv partials: (1568,2) grid, 64-row chunks, one matrix/block ----------
__global__ __launch_bounds__(256) void k_fc2_part(const float* __restrict__ hf,
    const float* __restrict__ wmu, const float* __restrict__ wlv,
    float* __restrict__ pmu, float* __restrict__ plv){
  __shared__ float sh[64];
  __shared__ float4 red[4][64];
  const int t = threadIdx.x, blk = blockIdx.x, f0 = blk*64;
  const int w = t>>6, l = t&63;
  const float* wsel = blockIdx.y ? wlv : wmu;
  float*       dsel = blockIdx.y ? plv : pmu;
  if(t < 64) sh[t] = hf[f0+t];
  __syncthreads();
  const float4* wp = (const float4*)(wsel + (size_t)(f0 + w*16)*256) + l;
  f32x4 a = {0.f,0.f,0.f,0.f};
  #pragma unroll
  for(int r=0; r<16; ++r){
    float h = sh[w*16 + r];
    float4 u = wp[r*64];
    a[0] += h*u.x; a[1] += h*u.y; a[2] += h*u.z; a[3] += h*u.w;
  }
  red[w][l] = (float4){a[0],a[1],a[2],a[3]};
  __syncthreads();
  const float* rr = (const float*)red;
  dsel[(size_t)blk*256 + t] = rr[t] + rr[256+t] + rr[512+t] + rr[768+t];
}

// ---------- reduce partials + reparametrize; block-per-output ----------
__global__ __launch_bounds__(256) void k_reparam_p(const float* __restrict__ pmu, const float* __restrict__ plv,
    const float* __restrict__ bmu, const float* __restrict__ blv, const float* __restrict__ eps,
    float* __restrict__ z, float* __restrict__ omu, float* __restrict__ olv){
  const int o = blockIdx.x, t = threadIdx.x;
  __shared__ float rm[4], rl[4];
  float sm = 0.f, sl = 0.f;
  for(int j=t; j<1568; j+=256){ sm += pmu[(size_t)j*256+o]; sl += plv[(size_t)j*256+o]; }
  #pragma unroll
  for(int off=32; off>=1; off>>=1){ sm += __shfl_xor(sm, off); sl += __shfl_xor(sl, off); }
  if((t&63)==0){ rm[t>>6]=sm; rl[t>>6]=sl; }
  __syncthreads();
  if(t==0){
    float mu = bmu[o] + rm[0]+rm[1]+rm[2]+rm[3];
    float lv = blv[o] + rl[0]+rl[1]+rl[2]+rl[3];
    z[o] = mu + eps[o] * expf(0.5f*lv);
    omu[o] = mu;
    olv[o] = lv;
  }
}

// ---------- decoder fc partials: (98, OSPL) grid ----------
template<int OSPL>
__global__ __launch_bounds__(256) void k_fc_dec_p(const float* __restrict__ z, const float* __restrict__ w,
    float* __restrict__ pfd){
  constexpr int OPC = 256/OSPL;
  __shared__ float sz[OPC];
  const int t = threadIdx.x, blk = blockIdx.x, os = blockIdx.y;
  if(t<OPC) sz[t] = z[os*OPC + t];
  __syncthreads();
  const size_t f4 = (size_t)blk*256 + t;        // float4 index into 25088
  const float4* wp = (const float4*)w + (size_t)os*OPC*25088 + f4;
  f32x4 a = {0.f,0.f,0.f,0.f};
  #pragma unroll 8
  for(int o=0;o<OPC;++o){
    float zz = sz[o];
    float4 u = wp[(size_t)o*25088];
    a[0] += zz*u.x; a[1] += zz*u.y; a[2] += zz*u.z; a[3] += zz*u.w;
  }
  ((float4*)pfd)[(size_t)os*25088 + f4] = (float4){a[0],a[1],a[2],a[3]};
}

// ---------- decoder fc combine: relu(sum partials + bias) ----------
template<int OSPL>
__global__ __launch_bounds__(256) void k_fc_dec_c(const float* __restrict__ pfd, const float* __restrict__ b,
    float* __restrict__ out){
  const int i = blockIdx.x*256 + threadIdx.x;   // float4 index
  const float4* p4 = (const float4*)pfd;
  float4 bb = ((const float4*)b)[i];
  f32x4 s = {bb.x, bb.y, bb.z, bb.w};
  #pragma unroll
  for(int k=0;k<OSPL;++k){
    float4 u = p4[(size_t)k*25088 + i];
    s[0] += u.x; s[1] += u.y; s[2] += u.z; s[3] += u.w;
  }
  ((float4*)out)[i] = (float4){fmaxf(s[0],0.f), fmaxf(s[1],0.f), fmaxf(s[2],0.f), fmaxf(s[3],0.f)};
}

// ---------- transposed conv 3x3 s2 p1 op1, parity-decomposed ----------
template<int CIN, int COUT, int ACT>
__global__ __launch_bounds__(256) void k_deconv_p(const float* __restrict__ in, const float* __restrict__ w,
    const float* __restrict__ bias, float* __restrict__ out, int Hin, int Win){
  __shared__ float wl[CIN*9];
  const int oc = blockIdx.y;
  const int tid = threadIdx.x;
  for(int i=tid; i<CIN*9; i+=256) wl[i] = w[((i/9)*COUT + oc)*9 + (i%9)];
  __syncthreads();
  const int nq = Hin*Win;
  const int code = blockIdx.x*256 + tid;
  if(code >= 4*nq) return;
  const int q = code % nq;
  const int pcode = code / nq;
  const int px = pcode & 1, py = pcode >> 1;
  const int qy = q / Win, qx = q - qy*Win;
  const float m1x = (qx+1 < Win) ? 1.f : 0.f;
  const float m1y = (qy+1 < Hin) ? 1.f : 0.f;
  const int qxc = (qx+1 < Win) ? qx+1 : qx;
  const int qyc = (qy+1 < Hin) ? qy+1 : qy;
  const int o00 = qy*Win+qx, o01 = qy*Win+qxc, o10 = qyc*Win+qx, o11 = qyc*Win+qxc;
  const int HW = nq;
  float acc = bias[oc];
  if(pcode == 0){
    #pragma unroll 4
    for(int ic=0; ic<CIN; ++ic) acc += in[ic*HW + o00] * wl[ic*9+4];
  } else if(pcode == 1){
    #pragma unroll 4
    for(int ic=0; ic<CIN; ++ic){
      acc += in[ic*HW + o00] * wl[ic*9+5];
      acc += (in[ic*HW + o01]*m1x) * wl[ic*9+3];
    }
  } else if(pcode == 2){
    #pragma unroll 4
    for(int ic=0; ic<CIN; ++ic){
      acc += in[ic*HW + o00] * wl[ic*9+7];
      acc += (in[ic*HW + o10]*m1y) * wl[ic*9+1];
    }
  } else {
    #pragma unroll 4
    for(int ic=0; ic<CIN; ++ic){
      acc += in[ic*HW + o00] * wl[ic*9+8];
      acc += (in[ic*HW + o01]*m1x) * wl[ic*9+6];
      acc += (in[ic*HW + o10]*m1y) * wl[ic*9+2];
      acc += (in[ic*HW + o11]*(m1x*m1y)) * wl[ic*9+0];
    }
  }
  const int oy = 2*qy+py, ox = 2*qx+px;
  float r = (ACT==0) ? fmaxf(acc, 0.f) : 1.f/(1.f + __expf(-acc));
  out[(oc*2*Hin + oy)*2*Win + ox] = r;
}

extern "C" void kernel_launch(void* const* d_in, const int* in_sizes, int n_in,
                              void* d_out, int out_size, void* d_ws, size_t ws_size,
                              hipStream_t stream){
  const float* X    = (const float*)d_in[0];
  const float* EPS  = (const float*)d_in[1];
  const float* c1w  = (const float*)d_in[2];  const float* c1b = (const float*)d_in[3];
  const float* q1w  = (const float*)d_in[4];  const float* q1b = (const float*)d_in[5];
  const float* k1w  = (const float*)d_in[6];  const float* k1b = (const float*)d_in[7];
  const float* v1w  = (const float*)d_in[8];  const float* v1b = (const float*)d_in[9];
  const float* g1   = (const float*)d_in[10];
  const float* c2w  = (const float*)d_in[11]; const float* c2b = (const float*)d_in[12];
  const float* q2w  = (const float*)d_in[13]; const float* q2b = (const float*)d_in[14];
  const float* k2w  = (const float*)d_in[15]; const float* k2b = (const float*)d_in[16];
  const float* v2w  = (const float*)d_in[17]; const float* v2b = (const float*)d_in[18];
  const float* g2   = (const float*)d_in[19];
  const float* c3w  = (const float*)d_in[20]; const float* c3b = (const float*)d_in[21];
  const float* fmw  = (const float*)d_in[22]; const float* fmb = (const float*)d_in[23];
  const float* flw  = (const float*)d_in[24]; const float* flb = (const float*)d_in[25];
  const float* fdw  = (const float*)d_in[26]; const float* fdb = (const float*)d_in[27];
  const float* d1w  = (const float*)d_in[28]; const float* d1b = (const float*)d_in[29];
  const float* d2w  = (const float*)d_in[30]; const float* d2b = (const float*)d_in[31];
  const float* d3w  = (const float*)d_in[32]; const float* d3b = (const float*)d_in[33];

  float* ws  = (float*)d_ws;
  float* h1  = ws;            // 401408
  float* h1a = h1  + 401408;  // 401408
  float* q1  = h1a + 401408;  // 50176
  float* k1  = q1  + 50176;   // 50176
  float* v1f = k1  + 50176;   // 401408 slot; bf16 [32][12544]
  float* h2  = v1f + 401408;  // 200704
  float* h2a = h2  + 200704;  // 200704
  float* q2  = h2a + 200704;  // 25088
  float* k2  = q2  + 25088;   // 25088
  float* v2f = k2  + 25088;   // 200704 slot; bf16 [64][3136]
  float* h3  = v2f + 200704;  // 100352
  float* z   = h3  + 100352 + 200704;  // 256
  float* part= h3  + 100352 + 200704 + 256;  // attn partial region
  bf16* v1b_ = (bf16*)v1f;
  bf16* v2b_ = (bf16*)v2f;
  // fc partials alias the (dead-by-then) attn partial region:
  float* pmu = part;              // [1568][256] = 401408
  float* plv = part + 401408;     // [1568][256] = 401408
  float* pfd = part + 802816;     // up to [16][100352] = 1605632
  // decoder buffers alias dead encoder regions:
  float* dd0 = h1;            // 100352
  float* dd1 = h1 + 100352;   // 200704
  float* dd2 = h1a;           // 401408

  const size_t base = 2258176;
  const bool big = ws_size >= (base + 2809856 + 87808) * 4;  // NSPLIT=7 footprint
  float* pdn = part + (big ? 2809856 : 802816);

  float* OUT = (float*)d_out;   // [recon 150528 | mu 256 | logvar 256], all f32

  k_conv_s2t<3><<<dim3(49,32),dim3(256),0,stream>>>(X, c1w, c1b, h1, 224, 224);
  k_qkv<32,4,4><<<dim3(196),dim3(256),0,stream>>>(h1, q1w,q1b, k1w,k1b, v1w,v1b, q1,k1,v1b_, 12544);
  if(big){
    k_attn_mfma<32,4,128,7,2><<<dim3(686),dim3(256),0,stream>>>(q1,k1,v1b_, part, pdn, 12544);
    k_attn_combT<32,7><<<dim3(196),dim3(256),0,stream>>>(part, pdn, h1, g1, h1a, 12544);
  } else {
    k_attn_mfma<32,4,128,2,2><<<dim3(196),dim3(256),0,stream>>>(q1,k1,v1b_, part, pdn, 12544);
    k_attn_combT<32,2><<<dim3(196),dim3(256),0,stream>>>(part, pdn, h1, g1, h1a, 12544);
  }
  k_conv_s2t<32><<<dim3(13,64),dim3(256),0,stream>>>(h1a, c2w, c2b, h2, 112, 112);
  k_qkv<64,8,8><<<dim3(98),dim3(256),0,stream>>>(h2, q2w,q2b, k2w,k2b, v2w,v2b, q2,k2,v2b_, 3136);
  if(big){
    k_attn_mfma<64,8,64,7,1><<<dim3(343),dim3(256),0,stream>>>(q2,k2,v2b_, part, pdn, 3136);
    k_attn_combT<64,7><<<dim3(49),dim3(256),0,stream>>>(part, pdn, h2, g2, h2a, 3136);
  } else {
    k_attn_mfma<64,8,64,1,1><<<dim3(49),dim3(256),0,stream>>>(q2,k2,v2b_, part, pdn, 3136);
    k_attn_combT<64,1><<<dim3(49),dim3(256),0,stream>>>(part, pdn, h2, g2, h2a, 3136);
  }
  k_conv_s2t<64><<<dim3(4,128),dim3(256),0,stream>>>(h2a, c3w, c3b, h3, 56, 56);
  k_fc2_part<<<dim3(1568,2),dim3(256),0,stream>>>(h3, fmw, flw, pmu, plv);
  k_reparam_p<<<dim3(256),dim3(256),0,stream>>>(pmu, plv, fmb, flb, EPS, z, OUT+150528, OUT+150784);
  if(big){
    k_fc_dec_p<16><<<dim3(98,16),dim3(256),0,stream>>>(z, fdw, pfd);
    k_fc_dec_c<16><<<dim3(98),dim3(256),0,stream>>>(pfd, fdb, dd0);
  } else {
    k_fc_dec_p<4><<<dim3(98,4),dim3(256),0,stream>>>(z, fdw, pfd);
    k_fc_dec_c<4><<<dim3(98),dim3(256),0,stream>>>(pfd, fdb, dd0);
  }
  k_deconv_p<128,64,0><<<dim3(13,64),dim3(256),0,stream>>>(dd0, d1w, d1b, dd1, 28,28);
  k_deconv_p<64,32,0><<<dim3(49,32),dim3(256),0,stream>>>(dd1, d2w, d2b, dd2, 56,56);
  k_deconv_p<32,3,1><<<dim3(196,3),dim3(256),0,stream>>>(dd2, d3w, d3b, OUT, 112,112);
}

// Round 13
// 348.122 us; speedup vs baseline: 1.1210x; 1.0103x over previous
//
#include <hip/hip_runtime.h>
#include <hip/hip_bf16.h>

typedef __hip_bfloat16 bf16;
typedef __attribute__((ext_vector_type(8))) short short8v;   // 8 x bf16 (4 VGPR) MFMA frag
typedef __attribute__((ext_vector_type(4))) float f32x4;

__device__ __forceinline__ unsigned int cvtpk(float lo, float hi){
  unsigned int r;
  asm("v_cvt_pk_bf16_f32 %0, %1, %2" : "=v"(r) : "v"(lo), "v"(hi));
  return r;
}
__device__ __forceinline__ float exp2a(float x){
  float r;
  asm("v_exp_f32 %0, %1" : "=v"(r) : "v"(x));
  return r;
}
__device__ __forceinline__ float blo(unsigned u){ return __uint_as_float(u<<16); }
__device__ __forceinline__ float bhi(unsigned u){ return __uint_as_float(u & 0xffff0000u); }

// ---------- conv 3x3 stride2 pad1 + relu; per-oc block, LDS weights, branch-free ----------
template<int CIN>
__global__ __launch_bounds__(256) void k_conv_s2t(const float* __restrict__ in, const float* __restrict__ w,
    const float* __restrict__ bias, float* __restrict__ out, int Hin, int Win){
  const int Hout = Hin>>1, Wout = Win>>1, HW = Hout*Wout;
  __shared__ float wl[CIN*9];
  const int oc = blockIdx.y, tid = threadIdx.x;
  for(int i=tid;i<CIN*9;i+=256) wl[i] = w[oc*CIN*9 + i];
  __syncthreads();
  const int idx = blockIdx.x*256 + tid;
  if(idx >= HW) return;
  const int oy = idx/Wout, ox = idx - oy*Wout;
  const int iy0 = 2*oy-1, ix0 = 2*ox-1;
  const float mt = iy0>=0 ? 1.f:0.f, ml = ix0>=0 ? 1.f:0.f;
  const int iyc = iy0<0?0:iy0, ixc = ix0<0?0:ix0;
  const int x1 = ix0+1, x2 = ix0+2;
  float acc = bias[oc];
  #pragma unroll 4
  for(int ic=0; ic<CIN; ++ic){
    const float* b0 = in + (ic*Hin + iyc )*Win;
    const float* b1 = in + (ic*Hin + iy0+1)*Win;
    const float* b2 = in + (ic*Hin + iy0+2)*Win;
    const float* wp = wl + ic*9;
    float t00 = b0[ixc]*(mt*ml), t01 = b0[x1]*mt, t02 = b0[x2]*mt;
    float t10 = b1[ixc]*ml,      t11 = b1[x1],    t12 = b1[x2];
    float t20 = b2[ixc]*ml,      t21 = b2[x1],    t22 = b2[x2];
    acc += t00*wp[0]+t01*wp[1]+t02*wp[2]
         + t10*wp[3]+t11*wp[4]+t12*wp[5]
         + t20*wp[6]+t21*wp[7]+t22*wp[8];
  }
  out[oc*HW + idx] = fmaxf(acc, 0.f);
}

// ---------- q/k/v projections, TPN threads per token; v stored bf16 ----------
template<int C, int O, int TPN>
__global__ __launch_bounds__(256) void k_qkv(const float* __restrict__ x,  // [C][N]
    const float* __restrict__ wq, const float* __restrict__ bq,
    const float* __restrict__ wk, const float* __restrict__ bk,
    const float* __restrict__ wv, const float* __restrict__ bv,
    float* __restrict__ q, float* __restrict__ k, bf16* __restrict__ v, int N){
  constexpr int NPB = 256/TPN;
  constexpr int OP = O/TPN > 0 ? O/TPN : 1;
  constexpr int CP = C/TPN;
  const int n = blockIdx.x*NPB + threadIdx.x/TPN;
  const int p = threadIdx.x%TPN;
  float xc[C];
  #pragma unroll
  for(int c=0;c<C;++c) xc[c] = x[c*N+n];
  #pragma unroll
  for(int oo=0;oo<OP;++oo){
    int o = p*OP + oo;
    float aq = bq[o], ak = bk[o];
    #pragma unroll
    for(int c=0;c<C;++c){ aq += wq[o*C+c]*xc[c]; ak += wk[o*C+c]*xc[c]; }
    q[n*O+o] = aq;
    k[o*N+n] = ak;
  }
  #pragma unroll
  for(int cc=0;cc<CP;++cc){
    int o = p*CP + cc;
    float av = bv[o];
    #pragma unroll
    for(int c=0;c<C;++c) av += wv[o*C+c]*xc[c];
    v[o*N+n] = __float2bfloat16(av);
  }
}

// ---------- MFMA flash attention, key-split, QG q-groups/wave, dbuf LDS, bf16 K ----------
// K stored packed bf16 (row = O bf16 = O/2 dwords) -> ds_read_b64/b128 per key, halving
// K LDS-pipe cost vs f32. Q stays f32 (pre-scaled by log2e); scores unpack K + FMA.
template<int C, int O, int ST, int NSPLIT, int QG>
__global__ __launch_bounds__(256) void k_attn_mfma(
    const float* __restrict__ q, const float* __restrict__ kk, const bf16* __restrict__ vb,
    float* __restrict__ pacc, float* __restrict__ pden, int N){
  constexpr int NT = C/16;
  constexpr int OH = O/2;                // dwords per packed K row
  constexpr int VROW = ST*2 + 16;        // bytes
  constexpr int VIT  = C*(ST/8)/256;     // uint4 stages per thread
  __shared__ __align__(16) char vsm[2][C*VROW];
  __shared__ unsigned int ksmu[2][(ST + ST/8)*OH];
  const int tid = threadIdx.x;
  const int qblk = blockIdx.x / NSPLIT, split = blockIdx.x % NSPLIT;
  const int KEYS = N / NSPLIT;
  const int kbase = split * KEYS;
  const int wv = tid >> 6;
  const int l  = tid & 63;
  const int lg = l >> 4, lq = l & 15;
  const int qbase = qblk*(64*QG) + wv*(16*QG);
  float qv[QG][O];
  #pragma unroll
  for(int g=0; g<QG; ++g)
    #pragma unroll
    for(int o=0;o<O;++o) qv[g][o] = q[(qbase + g*16 + lq)*O + o] * 1.44269504f;
  f32x4 acc[QG][NT];
  #pragma unroll
  for(int g=0; g<QG; ++g)
    #pragma unroll
    for(int nt=0;nt<NT;++nt) acc[g][nt] = (f32x4){0.f,0.f,0.f,0.f};
  float den[QG];
  #pragma unroll
  for(int g=0; g<QG; ++g) den[g] = 0.f;

  unsigned int kregu[OH];
  uint4  vreg[VIT];
  const bool kact = tid < ST;

  auto LOAD = [&](int g0){
    if(kact){
      #pragma unroll
      for(int h=0;h<OH;++h)
        kregu[h] = cvtpk(kk[(2*h+0)*N + kbase + g0 + tid],
                         kk[(2*h+1)*N + kbase + g0 + tid]);
    }
    #pragma unroll
    for(int i=0;i<VIT;++i){
      int ch = i*256 + tid;
      int c = ch/(ST/8), j8 = ch%(ST/8);
      vreg[i] = *(const uint4*)(vb + (size_t)c*N + kbase + g0 + j8*8);
    }
  };
  auto STORE = [&](int b){
    if(kact){
      int row = tid + (tid>>3);
      if constexpr(O==4){
        *(uint2*)&ksmu[b][row*OH] = make_uint2(kregu[0], kregu[1]);
      } else {
        *(uint4*)&ksmu[b][row*OH] = make_uint4(kregu[0], kregu[1], kregu[2], kregu[3]);
      }
    }
    #pragma unroll
    for(int i=0;i<VIT;++i){
      int ch = i*256 + tid;
      int c = ch/(ST/8), j8 = ch%(ST/8);
      *(uint4*)(vsm[b] + c*VROW + j8*16) = vreg[i];
    }
  };

  const int NTILE = KEYS/ST;
  LOAD(0);
  STORE(0);
  __syncthreads();
  int cur = 0;
  for(int t=0; t<NTILE; ++t){
    if(t+1 < NTILE) LOAD((t+1)*ST);
    #pragma unroll
    for(int s=0; s<ST/32; ++s){
      float pr[QG][8];
      #pragma unroll
      for(int e=0; e<8; ++e){
        const int row = s*36 + lg*9 + e;       // padded row index
        unsigned kw[OH];
        if constexpr(O==4){
          uint2 t2 = *(const uint2*)&ksmu[cur][row*OH];
          kw[0]=t2.x; kw[1]=t2.y;
        } else {
          uint4 t4 = *(const uint4*)&ksmu[cur][row*OH];
          kw[0]=t4.x; kw[1]=t4.y; kw[2]=t4.z; kw[3]=t4.w;
        }
        float kf[O];
        #pragma unroll
        for(int h=0;h<OH;++h){ kf[2*h]=blo(kw[h]); kf[2*h+1]=bhi(kw[h]); }
        #pragma unroll
        for(int g=0; g<QG; ++g){
          float sc = 0.f;
          #pragma unroll
          for(int o=0;o<O;++o) sc = fmaf(qv[g][o], kf[o], sc);
          pr[g][e] = exp2a(sc);
        }
      }
      union { unsigned int u[4]; short8v s8; } pa[QG];
      #pragma unroll
      for(int g=0; g<QG; ++g){
        #pragma unroll
        for(int u=0; u<4; ++u) pa[g].u[u] = cvtpk(pr[g][2*u], pr[g][2*u+1]);
        #pragma unroll
        for(int e=0; e<8; ++e) den[g] += pr[g][e];
      }
      #pragma unroll
      for(int nt=0; nt<NT; ++nt){
        short8v bf_ = *(const short8v*)(vsm[cur] + (lq + nt*16)*VROW + (s*32 + lg*8)*2);
        #pragma unroll
        for(int g=0; g<QG; ++g)
          acc[g][nt] = __builtin_amdgcn_mfma_f32_16x16x32_bf16(pa[g].s8, bf_, acc[g][nt], 0,0,0);
      }
    }
    if(t+1 < NTILE) STORE(cur^1);
    __syncthreads();
    cur ^= 1;
  }
  #pragma unroll
  for(int g=0; g<QG; ++g){
    den[g] += __shfl_xor(den[g], 16);
    den[g] += __shfl_xor(den[g], 32);
    if(lg == 0) pden[(size_t)split*N + qbase + g*16 + lq] = den[g];
  }
  #pragma unroll
  for(int g=0; g<QG; ++g)
    #pragma unroll
    for(int nt=0; nt<NT; ++nt)
      #pragma unroll
      for(int r=0;r<4;++r){
        int qg_ = qbase + g*16 + lg*4 + r;
        pacc[((size_t)split*N + qg_)*C + nt*16 + lq] = acc[g][nt][r];
      }
}

// ---------- attention combine, token-major + LDS transpose (coalesced both phases) ----------
template<int C, int NSPLIT>
__global__ __launch_bounds__(256) void k_attn_combT(const float* __restrict__ pacc,
    const float* __restrict__ pden, const float* __restrict__ xin,
    const float* __restrict__ gamma, float* __restrict__ out, int N){
  __shared__ float tl[C][65];
  __shared__ float dl[64];
  const int t = threadIdx.x;
  const int m0 = blockIdx.x*64;
  if(t < 64){
    float d = 0.f;
    #pragma unroll
    for(int s=0;s<NSPLIT;++s) d += pden[(size_t)s*N + m0 + t];
    dl[t] = d;
  }
  constexpr int E = 64*C/256;
  #pragma unroll
  for(int e=0;e<E;++e){
    int f = e*256 + t;                 // f = ml*C + c  (linear in pacc)
    int ml = f/C, c = f - ml*C;
    float a = 0.f;
    #pragma unroll
    for(int s=0;s<NSPLIT;++s) a += pacc[(size_t)s*N*C + (size_t)m0*C + f];
    tl[c][ml] = a;
  }
  __syncthreads();
  const float gm = gamma[0];
  #pragma unroll
  for(int e=0;e<E;++e){
    int f = e*256 + t;                 // f = c*64 + ml (linear in out/xin)
    int c = f>>6, ml = f & 63;
    size_t gi = (size_t)c*N + m0 + ml;
    out[gi] = gm * tl[c][ml] / dl[ml] + xin[gi];
  }
}

// ---------- fc_mu / fc_lv partials: (1568,2) grid; non-temporal weight stream ----------
__global__ __launch_bounds__(256) void k_fc2_part(const float* __restrict__ hf,
    const float* __restrict__ wmu, const float* __restrict__ wlv,
    float* __restrict__ pmu, float* __restrict__ plv){
  __shared__ float sh[64];
  __shared__ f32x4 red[4][64];
  const int t = threadIdx.x, blk = blockIdx.x, f0 = blk*64;
  const int w = t>>6, l = t&63;
  const float* wsel = blockIdx.y ? wlv : wmu;
  float*       dsel = blockIdx.y ? plv : pmu;
  if(t < 64) sh[t] = hf[f0+t];
  __syncthreads();
  const f32x4* wp = (const f32x4*)(wsel + (size_t)(f0 + w*16)*256) + l;
  f32x4 a = {0.f,0.f,0.f,0.f};
  #pragma unroll
  for(int r=0; r<16; ++r){
    float h = sh[w*16 + r];
    f32x4 u = __builtin_nontemporal_load(&wp[r*64]);
    a += h*u;
  }
  red[w][l] = a;
  __syncthreads();
  const float* rr = (const float*)red;
  dsel[(size_t)blk*256 + t] = rr[t] + rr[256+t] + rr[512+t] + rr[768+t];
}

// ---------- reduce partials + reparametrize; block-per-output ----------
__global__ __launch_bounds__(256) void k_reparam_p(const float* __restrict__ pmu, const float* __restrict__ plv,
    const float* __restrict__ bmu, const float* __restrict__ blv, const float* __restrict__ eps,
    float* __restrict__ z, float* __restrict__ omu, float* __restrict__ olv){
  const int o = blockIdx.x, t = threadIdx.x;
  __shared__ float rm[4], rl[4];
  float sm = 0.f, sl = 0.f;
  for(int j=t; j<1568; j+=256){ sm += pmu[(size_t)j*256+o]; sl += plv[(size_t)j*256+o]; }
  #pragma unroll
  for(int off=32; off>=1; off>>=1){ sm += __shfl_xor(sm, off); sl += __shfl_xor(sl, off); }
  if((t&63)==0){ rm[t>>6]=sm; rl[t>>6]=sl; }
  __syncthreads();
  if(t==0){
    float mu = bmu[o] + rm[0]+rm[1]+rm[2]+rm[3];
    float lv = blv[o] + rl[0]+rl[1]+rl[2]+rl[3];
    z[o] = mu + eps[o] * expf(0.5f*lv);
    omu[o] = mu;
    olv[o] = lv;
  }
}

// ---------- decoder fc partials: (98, OSPL) grid; non-temporal weight stream ----------
template<int OSPL>
__global__ __launch_bounds__(256) void k_fc_dec_p(const float* __restrict__ z, const float* __restrict__ w,
    float* __restrict__ pfd){
  constexpr int OPC = 256/OSPL;
  __shared__ float sz[OPC];
  const int t = threadIdx.x, blk = blockIdx.x, os = blockIdx.y;
  if(t<OPC) sz[t] = z[os*OPC + t];
  __syncthreads();
  const size_t f4 = (size_t)blk*256 + t;        // float4 index into 25088
  const f32x4* wp = (const f32x4*)w + (size_t)os*OPC*25088 + f4;
  f32x4 a = {0.f,0.f,0.f,0.f};
  #pragma unroll 8
  for(int o=0;o<OPC;++o){
    float zz = sz[o];
    f32x4 u = __builtin_nontemporal_load(&wp[(size_t)o*25088]);
    a += zz*u;
  }
  ((f32x4*)pfd)[(size_t)os*25088 + f4] = a;
}

// ---------- decoder fc combine: relu(sum partials + bias) ----------
template<int OSPL>
__global__ __launch_bounds__(256) void k_fc_dec_c(const float* __restrict__ pfd, const float* __restrict__ b,
    float* __restrict__ out){
  const int i = blockIdx.x*256 + threadIdx.x;   // float4 index
  const f32x4* p4 = (const f32x4*)pfd;
  f32x4 s = ((const f32x4*)b)[i];
  #pragma unroll
  for(int k=0;k<OSPL;++k) s += p4[(size_t)k*25088 + i];
  s[0]=fmaxf(s[0],0.f); s[1]=fmaxf(s[1],0.f); s[2]=fmaxf(s[2],0.f); s[3]=fmaxf(s[3],0.f);
  ((f32x4*)out)[i] = s;
}

// ---------- transposed conv 3x3 s2 p1 op1, parity-decomposed ----------
template<int CIN, int COUT, int ACT>
__global__ __launch_bounds__(256) void k_deconv_p(const float* __restrict__ in, const float* __restrict__ w,
    const float* __restrict__ bias, float* __restrict__ out, int Hin, int Win){
  __shared__ float wl[CIN*9];
  const int oc = blockIdx.y;
  const int tid = threadIdx.x;
  for(int i=tid; i<CIN*9; i+=256) wl[i] = w[((i/9)*COUT + oc)*9 + (i%9)];
  __syncthreads();
  const int nq = Hin*Win;
  const int code = blockIdx.x*256 + tid;
  if(code >= 4*nq) return;
  const int q = code % nq;
  const int pcode = code / nq;
  const int px = pcode & 1, py = pcode >> 1;
  const int qy = q / Win, qx = q - qy*Win;
  const float m1x = (qx+1 < Win) ? 1.f : 0.f;
  const float m1y = (qy+1 < Hin) ? 1.f : 0.f;
  const int qxc = (qx+1 < Win) ? qx+1 : qx;
  const int qyc = (qy+1 < Hin) ? qy+1 : qy;
  const int o00 = qy*Win+qx, o01 = qy*Win+qxc, o10 = qyc*Win+qx, o11 = qyc*Win+qxc;
  const int HW = nq;
  float acc = bias[oc];
  if(pcode == 0){
    #pragma unroll 4
    for(int ic=0; ic<CIN; ++ic) acc += in[ic*HW + o00] * wl[ic*9+4];
  } else if(pcode == 1){
    #pragma unroll 4
    for(int ic=0; ic<CIN; ++ic){
      acc += in[ic*HW + o00] * wl[ic*9+5];
      acc += (in[ic*HW + o01]*m1x) * wl[ic*9+3];
    }
  } else if(pcode == 2){
    #pragma unroll 4
    for(int ic=0; ic<CIN; ++ic){
      acc += in[ic*HW + o00] * wl[ic*9+7];
      acc += (in[ic*HW + o10]*m1y) * wl[ic*9+1];
    }
  } else {
    #pragma unroll 4
    for(int ic=0; ic<CIN; ++ic){
      acc += in[ic*HW + o00] * wl[ic*9+8];
      acc += (in[ic*HW + o01]*m1x) * wl[ic*9+6];
      acc += (in[ic*HW + o10]*m1y) * wl[ic*9+2];
      acc += (in[ic*HW + o11]*(m1x*m1y)) * wl[ic*9+0];
    }
  }
  const int oy = 2*qy+py, ox = 2*qx+px;
  float r = (ACT==0) ? fmaxf(acc, 0.f) : 1.f/(1.f + __expf(-acc));
  out[(oc*2*Hin + oy)*2*Win + ox] = r;
}

extern "C" void kernel_launch(void* const* d_in, const int* in_sizes, int n_in,
                              void* d_out, int out_size, void* d_ws, size_t ws_size,
                              hipStream_t stream){
  const float* X    = (const float*)d_in[0];
  const float* EPS  = (const float*)d_in[1];
  const float* c1w  = (const float*)d_in[2];  const float* c1b = (const float*)d_in[3];
  const float* q1w  = (const float*)d_in[4];  const float* q1b = (const float*)d_in[5];
  const float* k1w  = (const float*)d_in[6];  const float* k1b = (const float*)d_in[7];
  const float* v1w  = (const float*)d_in[8];  const float* v1b = (const float*)d_in[9];
  const float* g1   = (const float*)d_in[10];
  const float* c2w  = (const float*)d_in[11]; const float* c2b = (const float*)d_in[12];
  const float* q2w  = (const float*)d_in[13]; const float* q2b = (const float*)d_in[14];
  const float* k2w  = (const float*)d_in[15]; const float* k2b = (const float*)d_in[16];
  const float* v2w  = (const float*)d_in[17]; const float* v2b = (const float*)d_in[18];
  const float* g2   = (const float*)d_in[19];
  const float* c3w  = (const float*)d_in[20]; const float* c3b = (const float*)d_in[21];
  const float* fmw  = (const float*)d_in[22]; const float* fmb = (const float*)d_in[23];
  const float* flw  = (const float*)d_in[24]; const float* flb = (const float*)d_in[25];
  const float* fdw  = (const float*)d_in[26]; const float* fdb = (const float*)d_in[27];
  const float* d1w  = (const float*)d_in[28]; const float* d1b = (const float*)d_in[29];
  const float* d2w  = (const float*)d_in[30]; const float* d2b = (const float*)d_in[31];
  const float* d3w  = (const float*)d_in[32]; const float* d3b = (const float*)d_in[33];

  float* ws  = (float*)d_ws;
  float* h1  = ws;            // 401408
  float* h1a = h1  + 401408;  // 401408
  float* q1  = h1a + 401408;  // 50176
  float* k1  = q1  + 50176;   // 50176
  float* v1f = k1  + 50176;   // 401408 slot; bf16 [32][12544]
  float* h2  = v1f + 401408;  // 200704
  float* h2a = h2  + 200704;  // 200704
  float* q2  = h2a + 200704;  // 25088
  float* k2  = q2  + 25088;   // 25088
  float* v2f = k2  + 25088;   // 200704 slot; bf16 [64][3136]
  float* h3  = v2f + 200704;  // 100352
  float* z   = h3  + 100352 + 200704;  // 256
  float* part= h3  + 100352 + 200704 + 256;  // attn partial region
  bf16* v1b_ = (bf16*)v1f;
  bf16* v2b_ = (bf16*)v2f;
  // fc partials alias the (dead-by-then) attn partial region:
  float* pmu = part;              // [1568][256] = 401408
  float* plv = part + 401408;     // [1568][256] = 401408
  float* pfd = part + 802816;     // up to [16][100352] = 1605632
  // decoder buffers alias dead encoder regions:
  float* dd0 = h1;            // 100352
  float* dd1 = h1 + 100352;   // 200704
  float* dd2 = h1a;           // 401408

  const size_t base = 2258176;
  const bool big = ws_size >= (base + 2809856 + 87808) * 4;  // NSPLIT=7 footprint
  float* pdn = part + (big ? 2809856 : 802816);

  float* OUT = (float*)d_out;   // [recon 150528 | mu 256 | logvar 256], all f32

  k_conv_s2t<3><<<dim3(49,32),dim3(256),0,stream>>>(X, c1w, c1b, h1, 224, 224);
  k_qkv<32,4,4><<<dim3(196),dim3(256),0,stream>>>(h1, q1w,q1b, k1w,k1b, v1w,v1b, q1,k1,v1b_, 12544);
  if(big){
    k_attn_mfma<32,4,128,7,2><<<dim3(686),dim3(256),0,stream>>>(q1,k1,v1b_, part, pdn, 12544);
    k_attn_combT<32,7><<<dim3(196),dim3(256),0,stream>>>(part, pdn, h1, g1, h1a, 12544);
  } else {
    k_attn_mfma<32,4,128,2,2><<<dim3(196),dim3(256),0,stream>>>(q1,k1,v1b_, part, pdn, 12544);
    k_attn_combT<32,2><<<dim3(196),dim3(256),0,stream>>>(part, pdn, h1, g1, h1a, 12544);
  }
  k_conv_s2t<32><<<dim3(13,64),dim3(256),0,stream>>>(h1a, c2w, c2b, h2, 112, 112);
  k_qkv<64,8,8><<<dim3(98),dim3(256),0,stream>>>(h2, q2w,q2b, k2w,k2b, v2w,v2b, q2,k2,v2b_, 3136);
  if(big){
    k_attn_mfma<64,8,64,7,1><<<dim3(343),dim3(256),0,stream>>>(q2,k2,v2b_, part, pdn, 3136);
    k_attn_combT<64,7><<<dim3(49),dim3(256),0,stream>>>(part, pdn, h2, g2, h2a, 3136);
  } else {
    k_attn_mfma<64,8,64,1,1><<<dim3(49),dim3(256),0,stream>>>(q2,k2,v2b_, part, pdn, 3136);
    k_attn_combT<64,1><<<dim3(49),dim3(256),0,stream>>>(part, pdn, h2, g2, h2a, 3136);
  }
  k_conv_s2t<64><<<dim3(4,128),dim3(256),0,stream>>>(h2a, c3w, c3b, h3, 56, 56);
  k_fc2_part<<<dim3(1568,2),dim3(256),0,stream>>>(h3, fmw, flw, pmu, plv);
  k_reparam_p<<<dim3(256),dim3(256),0,stream>>>(pmu, plv, fmb, flb, EPS, z, OUT+150528, OUT+150784);
  if(big){
    k_fc_dec_p<16><<<dim3(98,16),dim3(256),0,stream>>>(z, fdw, pfd);
    k_fc_dec_c<16><<<dim3(98),dim3(256),0,stream>>>(pfd, fdb, dd0);
  } else {
    k_fc_dec_p<4><<<dim3(98,4),dim3(256),0,stream>>>(z, fdw, pfd);
    k_fc_dec_c<4><<<dim3(98),dim3(256),0,stream>>>(pfd, fdb, dd0);
  }
  k_deconv_p<128,64,0><<<dim3(13,64),dim3(256),0,stream>>>(dd0, d1w, d1b, dd1, 28,28);
  k_deconv_p<64,32,0><<<dim3(49,32),dim3(256),0,stream>>>(dd1, d2w, d2b, dd2, 56,56);
  k_deconv_p<32,3,1><<<dim3(196,3),dim3(256),0,stream>>>(dd2, d3w, d3b, OUT, 112,112);
}